// Round 1
// baseline (588.695 us; speedup 1.0000x reference)
//
#include <hip/hip_runtime.h>

#define N_NODES 50000
#define N_EDGES 800000
#define D 128

// ---------------- graph build ----------------

__global__ void deg_kernel(const int* __restrict__ dst, int* __restrict__ deg) {
  int e = blockIdx.x * 256 + threadIdx.x;
  if (e < N_EDGES) atomicAdd(&deg[dst[e]], 1);
}

// single-block scan: exclusive prefix over deg -> row_start, plus inv = 1/(deg+1)
__global__ void scan_kernel(const int* __restrict__ deg, int* __restrict__ row_start,
                            float* __restrict__ inv) {
  __shared__ int buf[1024];
  __shared__ int carry_s;
  const int t = threadIdx.x;
  if (t == 0) carry_s = 0;
  __syncthreads();
  for (int base = 0; base < N_NODES; base += 4096) {
    int i0 = base + t * 4;
    int v[4];
#pragma unroll
    for (int j = 0; j < 4; ++j) {
      int i = i0 + j;
      v[j] = (i < N_NODES) ? deg[i] : 0;
    }
    int s = v[0] + v[1] + v[2] + v[3];
    buf[t] = s;
    __syncthreads();
    int run = s;
    for (int off = 1; off < 1024; off <<= 1) {
      int other = (t >= off) ? buf[t - off] : 0;
      __syncthreads();
      run += other;
      buf[t] = run;
      __syncthreads();
    }
    int excl = carry_s + run - s;  // exclusive prefix for this thread's 4 items
#pragma unroll
    for (int j = 0; j < 4; ++j) {
      int i = i0 + j;
      if (i < N_NODES) {
        row_start[i] = excl;
        inv[i] = 1.0f / (float)(v[j] + 1);
      }
      excl += v[j];
    }
    __syncthreads();              // everyone has read carry_s
    if (t == 1023) carry_s += run; // run at t=1023 == tile total
    __syncthreads();
  }
  if (t == 0) row_start[N_NODES] = carry_s;
}

__global__ void csr_kernel(const int* __restrict__ src, const int* __restrict__ dst,
                           const int* __restrict__ row_start, int* __restrict__ cursor,
                           int* __restrict__ csr) {
  int e = blockIdx.x * 256 + threadIdx.x;
  if (e < N_EDGES) {
    int d = dst[e];
    int p = atomicAdd(&cursor[d], 1);
    csr[row_start[d] + p] = src[e];
  }
}

// transpose the three weight matrices into ws: wT[k][o] = W[o][k]
__global__ void wtrans_kernel(const float* __restrict__ W1, const float* __restrict__ W2,
                              const float* __restrict__ W3, float* __restrict__ wT) {
  int g = blockIdx.x * 256 + threadIdx.x;
  if (g < 16384) {
    int k = g >> 7, o = g & 127;
    wT[g] = W1[o * 128 + k];
  } else if (g < 32768) {
    int l = g - 16384;
    int k = l >> 7, o = l & 127;
    wT[g] = W2[o * 128 + k];
  } else if (g < 40960) {
    int l = g - 32768;
    int k = l >> 6, o = l & 63;
    wT[g] = W3[o * 128 + k];
  }
}

// ---------------- per-layer kernels ----------------

// wave-per-node CSR gather: outA[n] = (h[n] + sum_nbr h[nbr]) * inv[n]
__global__ __launch_bounds__(256) void agg_kernel(const float* __restrict__ h,
    const int* __restrict__ row_start, const int* __restrict__ csr,
    const float* __restrict__ inv, float* __restrict__ outA) {
  int node = blockIdx.x * 4 + (threadIdx.x >> 6);
  int lane = threadIdx.x & 63;
  float2 acc = *((const float2*)(h + (size_t)node * D) + lane);
  int s = row_start[node], e = row_start[node + 1];
  for (int j = s; j < e; ++j) {
    int nb = csr[j];
    float2 v = *((const float2*)(h + (size_t)nb * D) + lane);
    acc.x += v.x;
    acc.y += v.y;
  }
  float iv = inv[node];
  acc.x *= iv;
  acc.y *= iv;
  *((float2*)(outA + (size_t)node * D) + lane) = acc;
}

// f32 GEMM: out[r][ob+o] = relu( A[r][:] . wT[:][ob+o] ), A: [N][128], wT: [128][DOUT]
// block = 64 rows x 64 outs, thread = 4x4
template <int DOUT, bool RELU>
__global__ __launch_bounds__(256) void gemm_kernel(const float* __restrict__ A,
    const float* __restrict__ wT, float* __restrict__ out) {
  __shared__ float aL[64 * 128];  // column-XOR-swizzled
  __shared__ float wL[128 * 64];  // linear [k][o]
  const int t = threadIdx.x;
  const int row0 = blockIdx.x * 64;
  const int ob = blockIdx.y * 64;

  {
    const float4* A4 = (const float4*)A;
#pragma unroll
    for (int i = 0; i < 8; ++i) {
      int g4 = t + i * 256;  // 0..2047 over 64 rows x 32 float4
      int r = g4 >> 5;
      int k4 = g4 & 31;
      int gr = row0 + r;
      float4 v = make_float4(0.f, 0.f, 0.f, 0.f);
      if (gr < N_NODES) v = A4[(size_t)gr * 32 + k4];
      int col = (k4 << 2) ^ (((r >> 3) & 7) << 2);  // swizzle preserves float4 blocks
      *(float4*)&aL[r * 128 + col] = v;
    }
    const float4* w4 = (const float4*)wT;
#pragma unroll
    for (int i = 0; i < 8; ++i) {
      int g4 = t + i * 256;  // 0..2047 over 128 k x 16 float4
      int k = g4 >> 4;
      int o4 = g4 & 15;
      float4 v = w4[k * (DOUT / 4) + (ob >> 2) + o4];
      *(float4*)&wL[k * 64 + (o4 << 2)] = v;
    }
  }
  __syncthreads();

  const int rowT = t >> 4, outT = t & 15;
  const int r0 = rowT * 4, o0 = outT * 4;
  const int swz = ((rowT >> 1) & 7) << 2;  // (r0+i)>>3 == rowT>>1 for i in 0..3
  float acc[4][4];
#pragma unroll
  for (int i = 0; i < 4; ++i)
#pragma unroll
    for (int j = 0; j < 4; ++j) acc[i][j] = 0.f;

#pragma unroll 4
  for (int k = 0; k < 128; ++k) {
    int kc = k ^ swz;
    float a0 = aL[(r0 + 0) * 128 + kc];
    float a1 = aL[(r0 + 1) * 128 + kc];
    float a2 = aL[(r0 + 2) * 128 + kc];
    float a3 = aL[(r0 + 3) * 128 + kc];
    float4 b = *(const float4*)&wL[k * 64 + o0];
    acc[0][0] += a0 * b.x; acc[0][1] += a0 * b.y; acc[0][2] += a0 * b.z; acc[0][3] += a0 * b.w;
    acc[1][0] += a1 * b.x; acc[1][1] += a1 * b.y; acc[1][2] += a1 * b.z; acc[1][3] += a1 * b.w;
    acc[2][0] += a2 * b.x; acc[2][1] += a2 * b.y; acc[2][2] += a2 * b.z; acc[2][3] += a2 * b.w;
    acc[3][0] += a3 * b.x; acc[3][1] += a3 * b.y; acc[3][2] += a3 * b.z; acc[3][3] += a3 * b.w;
  }

#pragma unroll
  for (int i = 0; i < 4; ++i) {
    int gr = row0 + r0 + i;
    if (gr < N_NODES) {
      float4 v;
      v.x = RELU ? fmaxf(acc[i][0], 0.f) : acc[i][0];
      v.y = RELU ? fmaxf(acc[i][1], 0.f) : acc[i][1];
      v.z = RELU ? fmaxf(acc[i][2], 0.f) : acc[i][2];
      v.w = RELU ? fmaxf(acc[i][3], 0.f) : acc[i][3];
      *(float4*)&out[(size_t)gr * DOUT + ob + o0] = v;
    }
  }
}

// ---------------- launch ----------------

extern "C" void kernel_launch(void* const* d_in, const int* in_sizes, int n_in,
                              void* d_out, int out_size, void* d_ws, size_t ws_size,
                              hipStream_t stream) {
  const float* x  = (const float*)d_in[0];
  const int* ei   = (const int*)d_in[1];
  const float* W1 = (const float*)d_in[2];
  const float* W2 = (const float*)d_in[3];
  const float* W3 = (const float*)d_in[4];
  const int* src = ei;
  const int* dst = ei + N_EDGES;
  float* out = (float*)d_out;

  // workspace layout (256B-aligned chunks)
  char* ws = (char*)d_ws;
  size_t off = 0;
  auto alloc = [&](size_t bytes) {
    void* p = ws + off;
    off += (bytes + 255) & ~(size_t)255;
    return p;
  };
  int* deg       = (int*)alloc(N_NODES * sizeof(int));
  int* row_start = (int*)alloc((N_NODES + 1) * sizeof(int));
  int* cursor    = (int*)alloc(N_NODES * sizeof(int));
  int* csr       = (int*)alloc(N_EDGES * sizeof(int));
  float* inv     = (float*)alloc(N_NODES * sizeof(float));
  float* wT      = (float*)alloc((16384 + 16384 + 8192) * sizeof(float));
  float* A       = (float*)alloc((size_t)N_NODES * D * sizeof(float));
  float* H       = (float*)alloc((size_t)N_NODES * D * sizeof(float));
  (void)ws_size;

  float* wT1 = wT;
  float* wT2 = wT + 16384;
  float* wT3 = wT + 32768;

  hipMemsetAsync(deg, 0, N_NODES * sizeof(int), stream);
  hipMemsetAsync(cursor, 0, N_NODES * sizeof(int), stream);

  const int eblocks = (N_EDGES + 255) / 256;
  deg_kernel<<<eblocks, 256, 0, stream>>>(dst, deg);
  scan_kernel<<<1, 1024, 0, stream>>>(deg, row_start, inv);
  csr_kernel<<<eblocks, 256, 0, stream>>>(src, dst, row_start, cursor, csr);
  wtrans_kernel<<<(40960 + 255) / 256, 256, 0, stream>>>(W1, W2, W3, wT);

  const int ablocks = N_NODES / 4;             // 12500, exact
  const int gblocks = (N_NODES + 63) / 64;     // 782

  // layer 1: x -> A -> H
  agg_kernel<<<ablocks, 256, 0, stream>>>(x, row_start, csr, inv, A);
  gemm_kernel<128, true><<<dim3(gblocks, 2), 256, 0, stream>>>(A, wT1, H);
  // layer 2: H -> A -> H
  agg_kernel<<<ablocks, 256, 0, stream>>>(H, row_start, csr, inv, A);
  gemm_kernel<128, true><<<dim3(gblocks, 2), 256, 0, stream>>>(A, wT2, H);
  // layer 3: H -> A -> out (relu applied to final output per reference)
  agg_kernel<<<ablocks, 256, 0, stream>>>(H, row_start, csr, inv, A);
  gemm_kernel<64, true><<<dim3(gblocks, 1), 256, 0, stream>>>(A, wT3, out);
}

// Round 4
// 461.224 us; speedup vs baseline: 1.2764x; 1.2764x over previous
//
#include <hip/hip_runtime.h>

#define N_NODES 50000
#define N_EDGES 800000
#define D 128

// ---------------- graph build ----------------

__global__ void deg_kernel(const int* __restrict__ dst, int* __restrict__ deg) {
  int e = blockIdx.x * 256 + threadIdx.x;
  if (e < N_EDGES) atomicAdd(&deg[dst[e]], 1);
}

// single-block scan (1024 thr = 16 waves), wave-shuffle based:
// exclusive prefix over deg -> row_start, plus inv = 1/(deg+1)
__global__ void scan_kernel(const int* __restrict__ deg, int* __restrict__ row_start,
                            float* __restrict__ inv) {
  __shared__ int wsum[16];
  __shared__ int carry_s;
  const int t = threadIdx.x;
  const int lane = t & 63, wid = t >> 6;
  if (t == 0) carry_s = 0;
  __syncthreads();
  for (int base = 0; base < N_NODES; base += 4096) {
    int i0 = base + t * 4;
    int v[4];
    int s = 0;
#pragma unroll
    for (int j = 0; j < 4; ++j) {
      int i = i0 + j;
      v[j] = (i < N_NODES) ? deg[i] : 0;
      s += v[j];
    }
    // wave-inclusive scan of s
    int run = s;
#pragma unroll
    for (int off = 1; off < 64; off <<= 1) {
      int o = __shfl_up(run, off);
      if (lane >= off) run += o;
    }
    if (lane == 63) wsum[wid] = run;
    __syncthreads();
    if (t < 16) {
      int w = wsum[t];
#pragma unroll
      for (int off = 1; off < 16; off <<= 1) {
        int o = __shfl_up(w, off, 16);
        if (t >= off) w += o;
      }
      wsum[t] = w;  // inclusive over wave sums
    }
    __syncthreads();
    int excl = carry_s + (wid ? wsum[wid - 1] : 0) + run - s;
#pragma unroll
    for (int j = 0; j < 4; ++j) {
      int i = i0 + j;
      if (i < N_NODES) {
        row_start[i] = excl;
        inv[i] = 1.0f / (float)(v[j] + 1);
      }
      excl += v[j];
    }
    __syncthreads();
    if (t == 0) carry_s += wsum[15];
    __syncthreads();
  }
  if (t == 0) row_start[N_NODES] = carry_s;
}

__global__ void csr_kernel(const int* __restrict__ src, const int* __restrict__ dst,
                           const int* __restrict__ row_start, int* __restrict__ cursor,
                           int* __restrict__ csr) {
  int e = blockIdx.x * 256 + threadIdx.x;
  if (e < N_EDGES) {
    int d = dst[e];
    int p = atomicAdd(&cursor[d], 1);
    csr[row_start[d] + p] = src[e];
  }
}

// transpose the three weight matrices into ws: wT[k][o] = W[o][k]
__global__ void wtrans_kernel(const float* __restrict__ W1, const float* __restrict__ W2,
                              const float* __restrict__ W3, float* __restrict__ wT) {
  int g = blockIdx.x * 256 + threadIdx.x;
  if (g < 16384) {
    int k = g >> 7, o = g & 127;
    wT[g] = W1[o * 128 + k];
  } else if (g < 32768) {
    int l = g - 16384;
    int k = l >> 7, o = l & 127;
    wT[g] = W2[o * 128 + k];
  } else if (g < 40960) {
    int l = g - 32768;
    int k = l >> 6, o = l & 63;
    wT[g] = W3[o * 128 + k];
  }
}

// ---------------- per-layer kernels ----------------

// CSR gather over DV-dim rows: out[n] = relu?( (G[n] + sum_nbr G[nbr]) * inv[n] )
// float4 lanes: L = DV/4 lanes per row, NPW = 64/L nodes per wave (2 or 4
// independent CSR streams per wave), 4-deep unrolled gather for MLP.
template <int DV, bool RELU>
__global__ __launch_bounds__(256) void agg_kernel(const float* __restrict__ G,
    const int* __restrict__ row_start, const int* __restrict__ csr,
    const float* __restrict__ inv, float* __restrict__ outA) {
  constexpr int L = DV / 4;    // lanes per row
  constexpr int NPW = 64 / L;  // nodes per wave
  const int wave = (blockIdx.x * 256 + threadIdx.x) >> 6;
  const int lane = threadIdx.x & 63;
  const int sub = lane / L;
  const int li = lane % L;
  const int node = wave * NPW + sub;

  const float4* hp = (const float4*)G;
  float4 acc = hp[(size_t)node * L + li];
  const int s = row_start[node], e = row_start[node + 1];
  int j = s;
  for (; j + 4 <= e; j += 4) {
    int n0 = csr[j + 0], n1 = csr[j + 1], n2 = csr[j + 2], n3 = csr[j + 3];
    float4 v0 = hp[(size_t)n0 * L + li];
    float4 v1 = hp[(size_t)n1 * L + li];
    float4 v2 = hp[(size_t)n2 * L + li];
    float4 v3 = hp[(size_t)n3 * L + li];
    acc.x += (v0.x + v1.x) + (v2.x + v3.x);
    acc.y += (v0.y + v1.y) + (v2.y + v3.y);
    acc.z += (v0.z + v1.z) + (v2.z + v3.z);
    acc.w += (v0.w + v1.w) + (v2.w + v3.w);
  }
  for (; j < e; ++j) {
    int nb = csr[j];
    float4 v = hp[(size_t)nb * L + li];
    acc.x += v.x; acc.y += v.y; acc.z += v.z; acc.w += v.w;
  }
  float iv = inv[node];
  acc.x *= iv; acc.y *= iv; acc.z *= iv; acc.w *= iv;
  if (RELU) {
    acc.x = fmaxf(acc.x, 0.f); acc.y = fmaxf(acc.y, 0.f);
    acc.z = fmaxf(acc.z, 0.f); acc.w = fmaxf(acc.w, 0.f);
  }
  ((float4*)outA)[(size_t)node * L + li] = acc;
}

// f32 GEMM: out[r][ob+o] = A[r][:] . wT[:][ob+o], A: [N][128], wT: [128][DOUT]
// block = 64 rows x 64 outs, thread = 4x4
template <int DOUT>
__global__ __launch_bounds__(256) void gemm_kernel(const float* __restrict__ A,
    const float* __restrict__ wT, float* __restrict__ out) {
  __shared__ float aL[64 * 128];  // column-XOR-swizzled
  __shared__ float wL[128 * 64];  // linear [k][o]
  const int t = threadIdx.x;
  const int row0 = blockIdx.x * 64;
  const int ob = blockIdx.y * 64;

  {
    const float4* A4 = (const float4*)A;
#pragma unroll
    for (int i = 0; i < 8; ++i) {
      int g4 = t + i * 256;  // 0..2047 over 64 rows x 32 float4
      int r = g4 >> 5;
      int k4 = g4 & 31;
      int gr = row0 + r;
      float4 v = make_float4(0.f, 0.f, 0.f, 0.f);
      if (gr < N_NODES) v = A4[(size_t)gr * 32 + k4];
      int col = (k4 << 2) ^ (((r >> 3) & 7) << 2);  // swizzle preserves float4 blocks
      *(float4*)&aL[r * 128 + col] = v;
    }
    const float4* w4 = (const float4*)wT;
#pragma unroll
    for (int i = 0; i < 8; ++i) {
      int g4 = t + i * 256;  // 0..2047 over 128 k x 16 float4
      int k = g4 >> 4;
      int o4 = g4 & 15;
      float4 v = w4[k * (DOUT / 4) + (ob >> 2) + o4];
      *(float4*)&wL[k * 64 + (o4 << 2)] = v;
    }
  }
  __syncthreads();

  const int rowT = t >> 4, outT = t & 15;
  const int r0 = rowT * 4, o0 = outT * 4;
  const int swz = ((rowT >> 1) & 7) << 2;  // (r0+i)>>3 == rowT>>1 for i in 0..3
  float acc[4][4];
#pragma unroll
  for (int i = 0; i < 4; ++i)
#pragma unroll
    for (int j = 0; j < 4; ++j) acc[i][j] = 0.f;

#pragma unroll 4
  for (int k = 0; k < 128; ++k) {
    int kc = k ^ swz;
    float a0 = aL[(r0 + 0) * 128 + kc];
    float a1 = aL[(r0 + 1) * 128 + kc];
    float a2 = aL[(r0 + 2) * 128 + kc];
    float a3 = aL[(r0 + 3) * 128 + kc];
    float4 b = *(const float4*)&wL[k * 64 + o0];
    acc[0][0] += a0 * b.x; acc[0][1] += a0 * b.y; acc[0][2] += a0 * b.z; acc[0][3] += a0 * b.w;
    acc[1][0] += a1 * b.x; acc[1][1] += a1 * b.y; acc[1][2] += a1 * b.z; acc[1][3] += a1 * b.w;
    acc[2][0] += a2 * b.x; acc[2][1] += a2 * b.y; acc[2][2] += a2 * b.z; acc[2][3] += a2 * b.w;
    acc[3][0] += a3 * b.x; acc[3][1] += a3 * b.y; acc[3][2] += a3 * b.z; acc[3][3] += a3 * b.w;
  }

#pragma unroll
  for (int i = 0; i < 4; ++i) {
    int gr = row0 + r0 + i;
    if (gr < N_NODES) {
      float4 v = make_float4(acc[i][0], acc[i][1], acc[i][2], acc[i][3]);
      *(float4*)&out[(size_t)gr * DOUT + ob + o0] = v;
    }
  }
}

// ---------------- launch ----------------

extern "C" void kernel_launch(void* const* d_in, const int* in_sizes, int n_in,
                              void* d_out, int out_size, void* d_ws, size_t ws_size,
                              hipStream_t stream) {
  const float* x  = (const float*)d_in[0];
  const int* ei   = (const int*)d_in[1];
  const float* W1 = (const float*)d_in[2];
  const float* W2 = (const float*)d_in[3];
  const float* W3 = (const float*)d_in[4];
  const int* src = ei;
  const int* dst = ei + N_EDGES;
  float* out = (float*)d_out;

  // workspace layout (256B-aligned chunks)
  char* ws = (char*)d_ws;
  size_t off = 0;
  auto alloc = [&](size_t bytes) {
    void* p = ws + off;
    off += (bytes + 255) & ~(size_t)255;
    return p;
  };
  int* deg       = (int*)alloc(N_NODES * sizeof(int));
  int* row_start = (int*)alloc((N_NODES + 1) * sizeof(int));
  int* cursor    = (int*)alloc(N_NODES * sizeof(int));
  int* csr       = (int*)alloc(N_EDGES * sizeof(int));
  float* inv     = (float*)alloc(N_NODES * sizeof(float));
  float* wT      = (float*)alloc((16384 + 16384 + 8192) * sizeof(float));
  float* G       = (float*)alloc((size_t)N_NODES * D * sizeof(float));
  float* H       = (float*)alloc((size_t)N_NODES * D * sizeof(float));
  (void)ws_size;

  float* wT1 = wT;
  float* wT2 = wT + 16384;
  float* wT3 = wT + 32768;

  hipMemsetAsync(deg, 0, N_NODES * sizeof(int), stream);
  hipMemsetAsync(cursor, 0, N_NODES * sizeof(int), stream);

  const int eblocks = (N_EDGES + 255) / 256;
  deg_kernel<<<eblocks, 256, 0, stream>>>(dst, deg);
  scan_kernel<<<1, 1024, 0, stream>>>(deg, row_start, inv);
  csr_kernel<<<eblocks, 256, 0, stream>>>(src, dst, row_start, cursor, csr);
  wtrans_kernel<<<(40960 + 255) / 256, 256, 0, stream>>>(W1, W2, W3, wT);

  const int gblocks = (N_NODES + 63) / 64;  // 782

  // layer l: G = h @ Wl^T, then h' = relu(agg(G))   [agg and GEMM commute]
  // layer 1: x -> G -> H
  gemm_kernel<128><<<dim3(gblocks, 2), 256, 0, stream>>>(x, wT1, G);
  agg_kernel<128, true><<<6250, 256, 0, stream>>>(G, row_start, csr, inv, H);
  // layer 2: H -> G -> H
  gemm_kernel<128><<<dim3(gblocks, 2), 256, 0, stream>>>(H, wT2, G);
  agg_kernel<128, true><<<6250, 256, 0, stream>>>(G, row_start, csr, inv, H);
  // layer 3: H -> G(64) -> out (final relu fused into agg)
  gemm_kernel<64><<<dim3(gblocks, 1), 256, 0, stream>>>(H, wT3, G);
  agg_kernel<64, true><<<3125, 256, 0, stream>>>(G, row_start, csr, inv, out);
}

// Round 5
// 451.233 us; speedup vs baseline: 1.3046x; 1.0221x over previous
//
#include <hip/hip_runtime.h>

#define N_NODES 50000
#define N_EDGES 800000
#define D 128

// ---------------- graph build ----------------

__global__ void deg_kernel(const int* __restrict__ dst, int* __restrict__ deg) {
  int e = blockIdx.x * 256 + threadIdx.x;
  if (e < N_EDGES) atomicAdd(&deg[dst[e]], 1);
}

// single-block scan (1024 thr = 16 waves), wave-shuffle based:
// exclusive prefix over deg -> row_start (+ cursor copy), plus inv = 1/(deg+1)
__global__ void scan_kernel(const int* __restrict__ deg, int* __restrict__ row_start,
                            int* __restrict__ cursor, float* __restrict__ inv) {
  __shared__ int wsum[16];
  __shared__ int carry_s;
  const int t = threadIdx.x;
  const int lane = t & 63, wid = t >> 6;
  if (t == 0) carry_s = 0;
  __syncthreads();
  for (int base = 0; base < N_NODES; base += 4096) {
    int i0 = base + t * 4;
    int v[4];
    int s = 0;
#pragma unroll
    for (int j = 0; j < 4; ++j) {
      int i = i0 + j;
      v[j] = (i < N_NODES) ? deg[i] : 0;
      s += v[j];
    }
    // wave-inclusive scan of s
    int run = s;
#pragma unroll
    for (int off = 1; off < 64; off <<= 1) {
      int o = __shfl_up(run, off);
      if (lane >= off) run += o;
    }
    if (lane == 63) wsum[wid] = run;
    __syncthreads();
    if (t < 16) {
      int w = wsum[t];
#pragma unroll
      for (int off = 1; off < 16; off <<= 1) {
        int o = __shfl_up(w, off, 16);
        if (t >= off) w += o;
      }
      wsum[t] = w;  // inclusive over wave sums
    }
    __syncthreads();
    int excl = carry_s + (wid ? wsum[wid - 1] : 0) + run - s;
#pragma unroll
    for (int j = 0; j < 4; ++j) {
      int i = i0 + j;
      if (i < N_NODES) {
        row_start[i] = excl;
        cursor[i] = excl;
        inv[i] = 1.0f / (float)(v[j] + 1);
      }
      excl += v[j];
    }
    __syncthreads();
    if (t == 0) carry_s += wsum[15];
    __syncthreads();
  }
  if (t == 0) row_start[N_NODES] = carry_s;
}

__global__ void csr_kernel(const int* __restrict__ src, const int* __restrict__ dst,
                           int* __restrict__ cursor, int* __restrict__ csr) {
  int e = blockIdx.x * 256 + threadIdx.x;
  if (e < N_EDGES) {
    int p = atomicAdd(&cursor[dst[e]], 1);  // cursor pre-seeded with row_start
    csr[p] = src[e];
  }
}

// transpose the three weight matrices into ws: wT[k][o] = W[o][k]
__global__ void wtrans_kernel(const float* __restrict__ W1, const float* __restrict__ W2,
                              const float* __restrict__ W3, float* __restrict__ wT) {
  int g = blockIdx.x * 256 + threadIdx.x;
  if (g < 16384) {
    int k = g >> 7, o = g & 127;
    wT[g] = W1[o * 128 + k];
  } else if (g < 32768) {
    int l = g - 16384;
    int k = l >> 7, o = l & 127;
    wT[g] = W2[o * 128 + k];
  } else if (g < 40960) {
    int l = g - 32768;
    int k = l >> 6, o = l & 63;
    wT[g] = W3[o * 128 + k];
  }
}

// ---------------- per-layer kernels ----------------

// CSR gather over DV-dim rows: out[n] = relu?( (G[n] + sum_nbr G[nbr]) * inv[n] )
// float4 lanes: L = DV/4 lanes per row, NPW = 64/L nodes per wave.
// 8-edge blocks + dual accumulators: coarse issue/wait granularity keeps
// ~8 row-gathers in flight per stream (issue-order MLP fix).
template <int DV, bool RELU>
__global__ __launch_bounds__(256) void agg_kernel(const float* __restrict__ G,
    const int* __restrict__ row_start, const int* __restrict__ csr,
    const float* __restrict__ inv, float* __restrict__ outA) {
  constexpr int L = DV / 4;    // lanes per row
  constexpr int NPW = 64 / L;  // nodes per wave
  const int wave = (blockIdx.x * 256 + threadIdx.x) >> 6;
  const int lane = threadIdx.x & 63;
  const int sub = lane / L;
  const int li = lane % L;
  const int node = wave * NPW + sub;

  const float4* hp = (const float4*)G;
  float4 acc = hp[(size_t)node * L + li];
  float4 acc2 = make_float4(0.f, 0.f, 0.f, 0.f);
  const int s = row_start[node], e = row_start[node + 1];
  int j = s;
  for (; j + 8 <= e; j += 8) {
    int n0 = csr[j + 0], n1 = csr[j + 1], n2 = csr[j + 2], n3 = csr[j + 3];
    int n4 = csr[j + 4], n5 = csr[j + 5], n6 = csr[j + 6], n7 = csr[j + 7];
    float4 v0 = hp[(size_t)n0 * L + li];
    float4 v1 = hp[(size_t)n1 * L + li];
    float4 v2 = hp[(size_t)n2 * L + li];
    float4 v3 = hp[(size_t)n3 * L + li];
    float4 v4 = hp[(size_t)n4 * L + li];
    float4 v5 = hp[(size_t)n5 * L + li];
    float4 v6 = hp[(size_t)n6 * L + li];
    float4 v7 = hp[(size_t)n7 * L + li];
    acc.x  += (v0.x + v1.x) + (v2.x + v3.x);
    acc.y  += (v0.y + v1.y) + (v2.y + v3.y);
    acc.z  += (v0.z + v1.z) + (v2.z + v3.z);
    acc.w  += (v0.w + v1.w) + (v2.w + v3.w);
    acc2.x += (v4.x + v5.x) + (v6.x + v7.x);
    acc2.y += (v4.y + v5.y) + (v6.y + v7.y);
    acc2.z += (v4.z + v5.z) + (v6.z + v7.z);
    acc2.w += (v4.w + v5.w) + (v6.w + v7.w);
  }
  for (; j + 4 <= e; j += 4) {
    int n0 = csr[j + 0], n1 = csr[j + 1], n2 = csr[j + 2], n3 = csr[j + 3];
    float4 v0 = hp[(size_t)n0 * L + li];
    float4 v1 = hp[(size_t)n1 * L + li];
    float4 v2 = hp[(size_t)n2 * L + li];
    float4 v3 = hp[(size_t)n3 * L + li];
    acc.x += (v0.x + v1.x) + (v2.x + v3.x);
    acc.y += (v0.y + v1.y) + (v2.y + v3.y);
    acc.z += (v0.z + v1.z) + (v2.z + v3.z);
    acc.w += (v0.w + v1.w) + (v2.w + v3.w);
  }
  for (; j < e; ++j) {
    int nb = csr[j];
    float4 v = hp[(size_t)nb * L + li];
    acc2.x += v.x; acc2.y += v.y; acc2.z += v.z; acc2.w += v.w;
  }
  acc.x += acc2.x; acc.y += acc2.y; acc.z += acc2.z; acc.w += acc2.w;
  float iv = inv[node];
  acc.x *= iv; acc.y *= iv; acc.z *= iv; acc.w *= iv;
  if (RELU) {
    acc.x = fmaxf(acc.x, 0.f); acc.y = fmaxf(acc.y, 0.f);
    acc.z = fmaxf(acc.z, 0.f); acc.w = fmaxf(acc.w, 0.f);
  }
  ((float4*)outA)[(size_t)node * L + li] = acc;
}

// f32 GEMM: out[r][ob+o] = A[r][:] . wT[:][ob+o], A: [N][128], wT: [128][DOUT]
// 64 rows x 64 outs per block, 4x4 per thread, k blocked by 4 so ALL LDS
// reads are ds_read_b128 (8 b128 ~ 96cy per 64 FMA = 128cy -> VALU-bound).
// A k-blocks XOR-swizzled by row so the 4-row b128 reads are 2-way (free).
template <int DOUT>
__global__ __launch_bounds__(256, 2) void gemm_kernel(const float* __restrict__ A,
    const float* __restrict__ wT, float* __restrict__ out) {
  __shared__ float aL[64 * 128];  // [row][kblk^(row&7) : 4]
  __shared__ float wL[128 * 64];  // [k][o]
  const int t = threadIdx.x;
  const int row0 = blockIdx.x * 64;
  const int ob = blockIdx.y * 64;

  {
    const float4* A4 = (const float4*)A;
    float4* aL4 = (float4*)aL;
#pragma unroll
    for (int i = 0; i < 8; ++i) {
      int g4 = t + i * 256;  // 0..2047 over 64 rows x 32 k-blocks
      int r = g4 >> 5;
      int kb = g4 & 31;
      int gr = row0 + r;
      float4 v = make_float4(0.f, 0.f, 0.f, 0.f);
      if (gr < N_NODES) v = A4[(size_t)gr * 32 + kb];
      aL4[r * 32 + (kb ^ (r & 7))] = v;
    }
    const float4* w4 = (const float4*)wT;
    float4* wL4 = (float4*)wL;
#pragma unroll
    for (int i = 0; i < 8; ++i) {
      int g4 = t + i * 256;  // 0..2047 over 128 k x 16 float4
      int k = g4 >> 4;
      int o4 = g4 & 15;
      wL4[k * 16 + o4] = w4[k * (DOUT / 4) + (ob >> 2) + o4];
    }
  }
  __syncthreads();

  const int rowT = t >> 4, outT = t & 15;
  const int r0 = rowT * 4;
  const float4* aL4 = (const float4*)aL;
  const float4* wL4 = (const float4*)wL;
  float acc[4][4];
#pragma unroll
  for (int i = 0; i < 4; ++i)
#pragma unroll
    for (int j = 0; j < 4; ++j) acc[i][j] = 0.f;

#pragma unroll 4
  for (int kb = 0; kb < 32; ++kb) {
    float4 a[4];
#pragma unroll
    for (int i = 0; i < 4; ++i) a[i] = aL4[(r0 + i) * 32 + (kb ^ ((r0 + i) & 7))];
#pragma unroll
    for (int j = 0; j < 4; ++j) {
      float4 b = wL4[(kb * 4 + j) * 16 + outT];
      float a0 = ((const float*)&a[0])[j];
      float a1 = ((const float*)&a[1])[j];
      float a2 = ((const float*)&a[2])[j];
      float a3 = ((const float*)&a[3])[j];
      acc[0][0] += a0 * b.x; acc[0][1] += a0 * b.y; acc[0][2] += a0 * b.z; acc[0][3] += a0 * b.w;
      acc[1][0] += a1 * b.x; acc[1][1] += a1 * b.y; acc[1][2] += a1 * b.z; acc[1][3] += a1 * b.w;
      acc[2][0] += a2 * b.x; acc[2][1] += a2 * b.y; acc[2][2] += a2 * b.z; acc[2][3] += a2 * b.w;
      acc[3][0] += a3 * b.x; acc[3][1] += a3 * b.y; acc[3][2] += a3 * b.z; acc[3][3] += a3 * b.w;
    }
  }

#pragma unroll
  for (int i = 0; i < 4; ++i) {
    int gr = row0 + r0 + i;
    if (gr < N_NODES) {
      float4 v = make_float4(acc[i][0], acc[i][1], acc[i][2], acc[i][3]);
      *(float4*)&out[(size_t)gr * DOUT + ob + (outT << 2)] = v;
    }
  }
}

// ---------------- launch ----------------

extern "C" void kernel_launch(void* const* d_in, const int* in_sizes, int n_in,
                              void* d_out, int out_size, void* d_ws, size_t ws_size,
                              hipStream_t stream) {
  const float* x  = (const float*)d_in[0];
  const int* ei   = (const int*)d_in[1];
  const float* W1 = (const float*)d_in[2];
  const float* W2 = (const float*)d_in[3];
  const float* W3 = (const float*)d_in[4];
  const int* src = ei;
  const int* dst = ei + N_EDGES;
  float* out = (float*)d_out;

  // workspace layout (256B-aligned chunks)
  char* ws = (char*)d_ws;
  size_t off = 0;
  auto alloc = [&](size_t bytes) {
    void* p = ws + off;
    off += (bytes + 255) & ~(size_t)255;
    return p;
  };
  int* deg       = (int*)alloc(N_NODES * sizeof(int));
  int* row_start = (int*)alloc((N_NODES + 1) * sizeof(int));
  int* cursor    = (int*)alloc(N_NODES * sizeof(int));
  int* csr       = (int*)alloc(N_EDGES * sizeof(int));
  float* inv     = (float*)alloc(N_NODES * sizeof(float));
  float* wT      = (float*)alloc((16384 + 16384 + 8192) * sizeof(float));
  float* G       = (float*)alloc((size_t)N_NODES * D * sizeof(float));
  float* H       = (float*)alloc((size_t)N_NODES * D * sizeof(float));
  (void)ws_size;

  float* wT1 = wT;
  float* wT2 = wT + 16384;
  float* wT3 = wT + 32768;

  hipMemsetAsync(deg, 0, N_NODES * sizeof(int), stream);

  const int eblocks = (N_EDGES + 255) / 256;
  deg_kernel<<<eblocks, 256, 0, stream>>>(dst, deg);
  scan_kernel<<<1, 1024, 0, stream>>>(deg, row_start, cursor, inv);
  csr_kernel<<<eblocks, 256, 0, stream>>>(src, dst, cursor, csr);
  wtrans_kernel<<<(40960 + 255) / 256, 256, 0, stream>>>(W1, W2, W3, wT);

  const int gblocks = (N_NODES + 63) / 64;  // 782

  // layer l: G = h @ Wl^T, then h' = relu(agg(G))   [agg and GEMM commute]
  // layer 1: x -> G -> H
  gemm_kernel<128><<<dim3(gblocks, 2), 256, 0, stream>>>(x, wT1, G);
  agg_kernel<128, true><<<6250, 256, 0, stream>>>(G, row_start, csr, inv, H);
  // layer 2: H -> G -> H
  gemm_kernel<128><<<dim3(gblocks, 2), 256, 0, stream>>>(H, wT2, G);
  agg_kernel<128, true><<<6250, 256, 0, stream>>>(G, row_start, csr, inv, H);
  // layer 3: H -> G(64) -> out (final relu fused into agg)
  gemm_kernel<64><<<dim3(gblocks, 1), 256, 0, stream>>>(H, wT3, G);
  agg_kernel<64, true><<<3125, 256, 0, stream>>>(G, row_start, csr, inv, out);
}